// Round 6
// baseline (300.790 us; speedup 1.0000x reference)
//
#include <hip/hip_runtime.h>
#include <hip/hip_bf16.h>
#include <math.h>

#define HID 2048
#define NH 16
#define NKV 8
#define HD 128
#define SEQ 2048
#define EPS 1e-6f
#define SCALE 0.08838834764831845f  // 128^-0.5

typedef __attribute__((ext_vector_type(8))) short bf8_t;   // 8 bf16 (4 VGPRs)
typedef __attribute__((ext_vector_type(4))) float f4_t;    // 4 fp32

__device__ __forceinline__ short f2bf(float f) {
    union { __hip_bfloat16 h; short s; } u;
    u.h = __float2bfloat16(f);
    return u.s;
}
__device__ __forceinline__ float bf2f(short s) {
    union { short s; __hip_bfloat16 h; } u;
    u.s = s;
    return __bfloat162float(u.h);
}
__device__ __forceinline__ bf8_t pack8(const float4& a, const float4& b) {
    bf8_t r;
    r[0] = f2bf(a.x); r[1] = f2bf(a.y); r[2] = f2bf(a.z); r[3] = f2bf(a.w);
    r[4] = f2bf(b.x); r[5] = f2bf(b.y); r[6] = f2bf(b.z); r[7] = f2bf(b.w);
    return r;
}
// async global->LDS DMA, 16 B per lane; per-lane global addr, lds dest = base + lane*16
__device__ __forceinline__ void gload16(const short* g, short* l) {
    __builtin_amdgcn_global_load_lds(
        (const __attribute__((address_space(1))) unsigned int*)g,
        (__attribute__((address_space(3))) unsigned int*)l, 16, 0, 0);
}

__device__ __forceinline__ float wave_reduce_sum(float v) {
#pragma unroll
    for (int off = 32; off > 0; off >>= 1) v += __shfl_xor(v, off);
    return v;
}

// ---------------- 1. fused prep: f2bf(w_qkv) | f2bf(w_o) | hidden RMSNorm ------
__global__ __launch_bounds__(256) void prep_kernel(
    const float* __restrict__ w_qkv, short* __restrict__ wqb,
    const float* __restrict__ w_o, short* __restrict__ wob,
    const float* __restrict__ x, const float* __restrict__ w,
    short* __restrict__ out) {
    int bid = blockIdx.x;
    int tid = threadIdx.x;
    if (bid < 4096) {  // w_qkv: 4096*2048/8 = 1048576 chunks
        int i = bid * 256 + tid;
        float4 a = *(const float4*)(w_qkv + (size_t)i * 8);
        float4 b = *(const float4*)(w_qkv + (size_t)i * 8 + 4);
        *(bf8_t*)(wqb + (size_t)i * 8) = pack8(a, b);
        return;
    }
    if (bid < 6144) {  // w_o: 524288 chunks
        int i = (bid - 4096) * 256 + tid;
        float4 a = *(const float4*)(w_o + (size_t)i * 8);
        float4 b = *(const float4*)(w_o + (size_t)i * 8 + 4);
        *(bf8_t*)(wob + (size_t)i * 8) = pack8(a, b);
        return;
    }
    int row = bid - 6144;
    const float* xr = x + (size_t)row * HID;
    float4 a = *(const float4*)(xr + tid * 8);
    float4 b = *(const float4*)(xr + tid * 8 + 4);
    float ss = a.x * a.x + a.y * a.y + a.z * a.z + a.w * a.w +
               b.x * b.x + b.y * b.y + b.z * b.z + b.w * b.w;
    ss = wave_reduce_sum(ss);
    __shared__ float part[4];
    __shared__ float s_scale;
    if ((tid & 63) == 0) part[tid >> 6] = ss;
    __syncthreads();
    if (tid == 0) {
        float t = part[0] + part[1] + part[2] + part[3];
        s_scale = rsqrtf(t / (float)HID + EPS);
    }
    __syncthreads();
    float sc = s_scale;
    float4 wa = *(const float4*)(w + tid * 8);
    float4 wb = *(const float4*)(w + tid * 8 + 4);
    float4 oa = make_float4(a.x * sc * wa.x, a.y * sc * wa.y,
                            a.z * sc * wa.z, a.w * sc * wa.w);
    float4 ob = make_float4(b.x * sc * wb.x, b.y * sc * wb.y,
                            b.z * sc * wb.z, b.w * sc * wb.w);
    *(bf8_t*)(out + (size_t)row * HID + tid * 8) = pack8(oa, ob);
}

// ---------------- 2/5. bf16 MFMA GEMM: C = A @ B^T, BK=64 ----------------
// 128x128 tile, 4 waves (2x2) x 64x64, mfma_f32_16x16x32_bf16.
// global_load_lds staging; unpadded LDS, slot = (chunk + row) & 7 XOR swizzle.
// MODE 0: fp32 store to Cf. MODE 1: qkv split -> Q bf16, Kp bf16, Vr bf16 ROW-major.
template <int MODE>
__global__ __launch_bounds__(256) void gemm_mfma_kernel(
    const short* __restrict__ A, const short* __restrict__ B,
    float* __restrict__ Cf, short* __restrict__ Q, short* __restrict__ Kp,
    short* __restrict__ Vr, int M, int N, int K) {
    __shared__ short As[128][64];
    __shared__ short Bs[128][64];
    int tid = threadIdx.x;
    int wv = tid >> 6, lane = tid & 63;
    int n16 = lane & 15, qd = lane >> 4;
    int m0 = blockIdx.y * 128, n0 = blockIdx.x * 128;
    int wm = (wv >> 1) * 64, wn = (wv & 1) * 64;
    int sr8 = lane >> 3, slot = lane & 7;

    size_t ainv[4], binv[4];
#pragma unroll
    for (int it = 0; it < 4; ++it) {
        int row = wv * 32 + it * 8 + sr8;
        int chunk = (slot - row) & 7;
        ainv[it] = (size_t)(m0 + row) * K + chunk * 8;
        binv[it] = (size_t)(n0 + row) * K + chunk * 8;
    }

    f4_t acc[4][4];
#pragma unroll
    for (int i = 0; i < 4; ++i)
#pragma unroll
        for (int j = 0; j < 4; ++j) acc[i][j] = (f4_t){0.f, 0.f, 0.f, 0.f};

    for (int k0 = 0; k0 < K; k0 += 64) {
        __syncthreads();
#pragma unroll
        for (int it = 0; it < 4; ++it) {
            gload16(A + ainv[it] + k0, &As[wv * 32 + it * 8][0]);
            gload16(B + binv[it] + k0, &Bs[wv * 32 + it * 8][0]);
        }
        __syncthreads();

        bf8_t af[4][2], bf[4][2];
#pragma unroll
        for (int t = 0; t < 4; ++t)
#pragma unroll
            for (int ks = 0; ks < 2; ++ks) {
                int ar = wm + t * 16 + n16;
                af[t][ks] = *(const bf8_t*)&As[ar][(((ks * 4 + qd) + ar) & 7) * 8];
                int br = wn + t * 16 + n16;
                bf[t][ks] = *(const bf8_t*)&Bs[br][(((ks * 4 + qd) + br) & 7) * 8];
            }
#pragma unroll
        for (int ks = 0; ks < 2; ++ks)
#pragma unroll
            for (int mt = 0; mt < 4; ++mt)
#pragma unroll
                for (int nt = 0; nt < 4; ++nt)
                    acc[mt][nt] = __builtin_amdgcn_mfma_f32_16x16x32_bf16(
                        af[mt][ks], bf[nt][ks], acc[mt][nt], 0, 0, 0);
    }

#pragma unroll
    for (int mt = 0; mt < 4; ++mt)
#pragma unroll
        for (int nt = 0; nt < 4; ++nt)
#pragma unroll
            for (int r = 0; r < 4; ++r) {
                int gm = m0 + wm + mt * 16 + qd * 4 + r;
                int gn = n0 + wn + nt * 16 + n16;
                float v = acc[mt][nt][r];
                if (MODE == 0) {
                    Cf[(size_t)gm * N + gn] = v;
                } else {
                    if (gn < NH * HD)
                        Q[(size_t)gm * (NH * HD) + gn] = f2bf(v);
                    else if (gn < (NH + NKV) * HD)
                        Kp[(size_t)gm * (NKV * HD) + (gn - NH * HD)] = f2bf(v);
                    else
                        Vr[(size_t)gm * (NKV * HD) + (gn - (NH + NKV) * HD)] = f2bf(v);
                }
            }
}

// ---------------- 3. fused mid: V transpose | q/k RMSNorm + RoPE ----------------
__global__ __launch_bounds__(256) void mid_kernel(
    const short* __restrict__ vr, short* __restrict__ vt,
    short* __restrict__ q, short* __restrict__ k,
    const float* __restrict__ qw, const float* __restrict__ kw,
    const int* __restrict__ pos) {
    int bid = blockIdx.x;
    int tid = threadIdx.x;
    if (bid < 512) {  // ---- V transpose, 64x64 tile ----
        __shared__ short t[64][64];  // chunk-swizzled
        int s0 = (bid & 31) * 64, d0 = (bid >> 5) * 64;
        int sl = tid >> 3, ch = tid & 7;
#pragma unroll
        for (int it = 0; it < 2; ++it) {
            int s_local = it * 32 + sl;
            bf8_t vv = *(const bf8_t*)(vr + (size_t)(s0 + s_local) * (NKV * HD) + d0 + ch * 8);
            *(bf8_t*)&t[s_local][((ch + s_local) & 7) * 8] = vv;
        }
        __syncthreads();
#pragma unroll
        for (int it = 0; it < 2; ++it) {
            int d_local = it * 32 + sl;
            int sbase = ch * 8;
            bf8_t o;
#pragma unroll
            for (int j = 0; j < 8; ++j) {
                int s = sbase + j;
                o[j] = t[s][(((d_local >> 3) + s) & 7) * 8 + (d_local & 7)];
            }
            *(bf8_t*)(vt + (size_t)(d0 + d_local) * SEQ + s0 + sbase) = o;
        }
        return;
    }
    // ---- q/k RMSNorm + RoPE: two 128-thread units per block ----
    int u = (bid - 512) * 2 + (tid >> 7);  // 0..49151
    int ui = tid >> 7, d = tid & 127;
    int s = u / 24, hh = u % 24;
    short* ptr;
    const float* w;
    if (hh < NH) {
        ptr = q + (size_t)s * (NH * HD) + hh * HD;
        w = qw;
    } else {
        ptr = k + (size_t)s * (NKV * HD) + (hh - NH) * HD;
        w = kw;
    }
    float x = bf2f(ptr[d]);
    float ss = wave_reduce_sum(x * x);
    __shared__ float part[2][2];
    if ((d & 63) == 0) part[ui][d >> 6] = ss;
    __syncthreads();
    float tot = part[ui][0] + part[ui][1];
    float xn = x * rsqrtf(tot / (float)HD + EPS) * w[d];
    __shared__ float sh[2][HD];
    sh[ui][d] = xn;
    __syncthreads();
    int j = d & 63;
    float inv = powf(10000.0f, -(float)(2 * j) * (1.0f / (float)HD));
    float fr = (float)pos[s] * inv;
    float sn, cs;
    sincosf(fr, &sn, &cs);
    float o;
    if (d < 64)
        o = xn * cs - sh[ui][d + 64] * sn;
    else
        o = xn * cs + sh[ui][d - 64] * sn;
    ptr[d] = f2bf(o);
}

// ---------------- 4. MFMA flash attention v4 (k-chunked) ----------------
// 256 threads = 4 waves; 64 q-rows/block; 64-key tiles double-buffered via
// global_load_lds; one barrier per tile. q-tiles with qb>=16 are split into
// two k-chunks (<=16 tiles) writing unnormalized partials; qb<=15 direct.
// 768 blocks, split-chunks dispatched first (exactly fills 2 blocks/CU),
// singles refill as slots free -> balanced, max serial chain 16 tiles.
__device__ __forceinline__ void attn_stage(
    short (&kb)[64][128], short (&vb)[128][64],
    const short* __restrict__ kg, const short* __restrict__ vg,
    int t0, const int (&kinv)[4], const int (&vinv)[4], int wv) {
#pragma unroll
    for (int it = 0; it < 4; ++it) {
        gload16(kg + (size_t)t0 * (NKV * HD) + kinv[it], &kb[wv * 16 + it * 4][0]);
        gload16(vg + t0 + vinv[it], &vb[wv * 32 + it * 8][0]);
    }
}

__device__ __forceinline__ void attn_tile(
    const short (&kb)[64][128], const short (&vb)[128][64],
    short (&psh)[4][16][72],
    const bf8_t (&qf)[4], f4_t (&of)[8],
    float (&m_i)[4], float (&l_p)[4],
    int wv, int n, int qd, bool diag) {
    f4_t sc[4];
#pragma unroll
    for (int kk = 0; kk < 4; ++kk) sc[kk] = (f4_t){0.f, 0.f, 0.f, 0.f};
#pragma unroll
    for (int kk = 0; kk < 4; ++kk) {
        int key = kk * 16 + n;
#pragma unroll
        for (int ks = 0; ks < 4; ++ks) {
            bf8_t kf = *(const bf8_t*)&kb[key][(((ks * 4 + qd) + key) & 15) * 8];
            sc[kk] = __builtin_amdgcn_mfma_f32_16x16x32_bf16(qf[ks], kf, sc[kk], 0, 0, 0);
        }
    }
    int rowb = wv * 16 + qd * 4;
#pragma unroll
    for (int kk = 0; kk < 4; ++kk)
#pragma unroll
        for (int r = 0; r < 4; ++r) {
            float s = sc[kk][r] * SCALE;
            if (diag && (kk * 16 + n > rowb + r)) s = -1e30f;
            sc[kk][r] = s;
        }
#pragma unroll
    for (int r = 0; r < 4; ++r) {
        float mx = fmaxf(fmaxf(sc[0][r], sc[1][r]), fmaxf(sc[2][r], sc[3][r]));
#pragma unroll
        for (int off = 1; off < 16; off <<= 1) mx = fmaxf(mx, __shfl_xor(mx, off));
        float mnew = fmaxf(m_i[r], mx);
        float al = __expf(m_i[r] - mnew);
        m_i[r] = mnew;
        float lsum = 0.f;
#pragma unroll
        for (int kk = 0; kk < 4; ++kk) {
            float p = __expf(sc[kk][r] - mnew);
            psh[wv][qd * 4 + r][kk * 16 + n] = f2bf(p);
            lsum += p;
        }
        l_p[r] = l_p[r] * al + lsum;
#pragma unroll
        for (int nb = 0; nb < 8; ++nb) of[nb][r] *= al;
    }
    __builtin_amdgcn_wave_barrier();  // psh write->read same wave, in-order LDS
#pragma unroll
    for (int ks2 = 0; ks2 < 2; ++ks2) {
        bf8_t pf = *(const bf8_t*)&psh[wv][n][ks2 * 32 + qd * 8];
#pragma unroll
        for (int nb = 0; nb < 8; ++nb) {
            int dim = nb * 16 + n;
            bf8_t vf = *(const bf8_t*)&vb[dim][(((ks2 * 4 + qd) + dim) & 7) * 8];
            of[nb] = __builtin_amdgcn_mfma_f32_16x16x32_bf16(pf, vf, of[nb], 0, 0, 0);
        }
    }
}

__global__ __launch_bounds__(256) void attn_chunk_kernel(
    const short* __restrict__ q, const short* __restrict__ k,
    const short* __restrict__ vt, short* __restrict__ o,
    short* __restrict__ opart, float* __restrict__ ml) {
    __shared__ short kbufA[64][128], kbufB[64][128];
    __shared__ short vbufA[128][64], vbufB[128][64];
    __shared__ short psh[4][16][72];

    int tid = threadIdx.x;
    int wv = tid >> 6, lane = tid & 63;
    int n = lane & 15, qd = lane >> 4;

    int bid = blockIdx.x;
    int h, qb, tstart, tcount, c;
    bool split;
    if (bid < 512) {  // split chunks (qb 16..31), heavy half dispatched first
        int id = bid;
        qb = 16 + (id >> 5);
        c = (id >> 4) & 1;
        h = id & 15;
        if (c == 0) { tstart = 0; tcount = 16; }
        else        { tstart = 16; tcount = qb - 15; }
        split = true;
    } else {          // singles (qb 15..0 descending)
        int id = bid - 512;
        qb = 15 - (id >> 4);
        h = id & 15;
        tstart = 0; tcount = qb + 1; c = 0;
        split = false;
    }
    bool dl = (tstart + tcount - 1 == qb);  // diag in last tile of this chunk
    int kvh = h >> 1;
    int qbase = qb * 64;

    int kinv[4], vinv[4];
#pragma unroll
    for (int it = 0; it < 4; ++it) {
        int key = wv * 16 + it * 4 + (lane >> 4);
        int ck = ((lane & 15) - key) & 15;
        kinv[it] = key * (NKV * HD) + kvh * HD + ck * 8;
        int dim = wv * 32 + it * 8 + (lane >> 3);
        int cv = ((lane & 7) - dim) & 7;
        vinv[it] = (kvh * HD + dim) * SEQ + cv * 8;
    }

    bf8_t qf[4];
    {
        const short* qp = q + (size_t)(qbase + wv * 16 + n) * (NH * HD) + h * HD + qd * 8;
#pragma unroll
        for (int ks = 0; ks < 4; ++ks) qf[ks] = *(const bf8_t*)(qp + ks * 32);
    }

    f4_t of[8];
#pragma unroll
    for (int i = 0; i < 8; ++i) of[i] = (f4_t){0.f, 0.f, 0.f, 0.f};
    float m_i[4] = {-1e30f, -1e30f, -1e30f, -1e30f};
    float l_p[4] = {0.f, 0.f, 0.f, 0.f};

    attn_stage(kbufA, vbufA, k, vt, tstart * 64, kinv, vinv, wv);
    for (int tt = 0; tt < tcount; tt += 2) {
        __syncthreads();  // drains DMA for tile tt (issued a full tile ago)
        if (tt + 1 < tcount)
            attn_stage(kbufB, vbufB, k, vt, (tstart + tt + 1) * 64, kinv, vinv, wv);
        attn_tile(kbufA, vbufA, psh, qf, of, m_i, l_p, wv, n, qd, dl && (tt == tcount - 1));
        if (tt + 1 < tcount) {
            __syncthreads();
            if (tt + 2 < tcount)
                attn_stage(kbufA, vbufA, k, vt, (tstart + tt + 2) * 64, kinv, vinv, wv);
            attn_tile(kbufB, vbufB, psh, qf, of, m_i, l_p, wv, n, qd, dl && (tt + 1 == tcount - 1));
        }
    }

    // cross-lane l reduction
    float lred[4];
#pragma unroll
    for (int r = 0; r < 4; ++r) {
        float l = l_p[r];
#pragma unroll
        for (int off = 1; off < 16; off <<= 1) l += __shfl_xor(l, off);
        lred[r] = l;
    }

    if (!split) {
#pragma unroll
        for (int nb = 0; nb < 8; ++nb)
#pragma unroll
            for (int r = 0; r < 4; ++r) {
                int row = qbase + wv * 16 + qd * 4 + r;
                o[(size_t)row * (NH * HD) + h * HD + nb * 16 + n] =
                    f2bf(of[nb][r] / lred[r]);
            }
    } else {
        size_t pb = ((size_t)h * 16 + (qb - 16)) * 2 + c;
        short* op = opart + pb * (64 * 128);
#pragma unroll
        for (int nb = 0; nb < 8; ++nb)
#pragma unroll
            for (int r = 0; r < 4; ++r) {
                int rl = wv * 16 + qd * 4 + r;
                op[rl * 128 + nb * 16 + n] = f2bf(of[nb][r]);
            }
        if (n == 0) {
#pragma unroll
            for (int r = 0; r < 4; ++r) {
                int rl = wv * 16 + qd * 4 + r;
                ml[pb * 128 + rl * 2] = m_i[r];
                ml[pb * 128 + rl * 2 + 1] = lred[r];
            }
        }
    }
}

// ---------------- 4b. merge partials for split q-tiles ----------------
__global__ __launch_bounds__(256) void attn_merge_kernel(
    const short* __restrict__ opart, const float* __restrict__ ml,
    short* __restrict__ o) {
    int bid = blockIdx.x;            // 256: h*16 + qi
    int h = bid & 15, qi = bid >> 4; // qb = 16+qi
    int tid = threadIdx.x;
    int r = tid >> 2, dq = tid & 3;  // row 0..63, dim quarter
    size_t pb0 = ((size_t)h * 16 + qi) * 2;
    size_t pb1 = pb0 + 1;
    float m0 = ml[pb0 * 128 + r * 2], l0 = ml[pb0 * 128 + r * 2 + 1];
    float m1 = ml[pb1 * 128 + r * 2], l1 = ml[pb1 * 128 + r * 2 + 1];
    float M = fmaxf(m0, m1);
    float w0 = __expf(m0 - M), w1 = __expf(m1 - M);
    float invL = 1.0f / (w0 * l0 + w1 * l1);
    int row = (16 + qi) * 64 + r;
#pragma unroll
    for (int j = 0; j < 4; ++j) {
        int d0 = dq * 32 + j * 8;
        bf8_t a = *(const bf8_t*)(opart + pb0 * (64 * 128) + r * 128 + d0);
        bf8_t b = *(const bf8_t*)(opart + pb1 * (64 * 128) + r * 128 + d0);
        bf8_t e;
#pragma unroll
        for (int i = 0; i < 8; ++i)
            e[i] = f2bf((w0 * bf2f(a[i]) + w1 * bf2f(b[i])) * invL);
        *(bf8_t*)(o + (size_t)row * (NH * HD) + h * HD + d0) = e;
    }
}

// ---------------- launch ----------------
extern "C" void kernel_launch(void* const* d_in, const int* in_sizes, int n_in,
                              void* d_out, int out_size, void* d_ws, size_t ws_size,
                              hipStream_t stream) {
    const int* positions   = (const int*)d_in[0];
    const float* hidden    = (const float*)d_in[1];
    const float* ln_w      = (const float*)d_in[2];
    const float* w_qkv     = (const float*)d_in[3];
    const float* w_o       = (const float*)d_in[4];
    const float* q_norm_w  = (const float*)d_in[5];
    const float* k_norm_w  = (const float*)d_in[6];
    float* out = (float*)d_out;

    char* base = (char*)d_ws;
    short* hnb   = (short*)(base);                        // 8 MB: hn bf16 -> attn-out bf16
    short* wqb   = (short*)(base + ((size_t)8 << 20));    // 16 MB: w_qkv bf16 (dead after gemm1)
    short* vtb   = (short*)(base + ((size_t)8 << 20));    // 4 MB: v^T (in dead wqb region)
    short* opart = (short*)(base + ((size_t)12 << 20));   // 8 MB: attn partials (dead wqb)
    float* mlbuf = (float*)(base + ((size_t)20 << 20));   // 256 KB: m/l partials
    short* wob   = (short*)(base + ((size_t)24 << 20));   // 8 MB: w_o bf16
    short* qbf   = (short*)(base + ((size_t)32 << 20));   // 8 MB: q bf16
    short* kbf   = (short*)(base + ((size_t)40 << 20));   // 4 MB: k bf16
    short* vrow  = (short*)(base + ((size_t)44 << 20));   // 4 MB: v bf16 row-major

    prep_kernel<<<8192, 256, 0, stream>>>(w_qkv, wqb, w_o, wob, hidden, ln_w, hnb);
    gemm_mfma_kernel<1><<<dim3(32, 16), 256, 0, stream>>>(
        hnb, wqb, nullptr, qbf, kbf, vrow, SEQ, (NH + 2 * NKV) * HD, HID);
    mid_kernel<<<512 + 24576, 256, 0, stream>>>(
        vrow, vtb, qbf, kbf, q_norm_w, k_norm_w, positions);
    attn_chunk_kernel<<<768, 256, 0, stream>>>(qbf, kbf, vtb, hnb, opart, mlbuf);
    attn_merge_kernel<<<256, 256, 0, stream>>>(opart, mlbuf, hnb);
    gemm_mfma_kernel<0><<<dim3(16, 16), 256, 0, stream>>>(
        hnb, wob, out, nullptr, nullptr, nullptr, SEQ, NH * HD, HID);
}

// Round 7
// 279.320 us; speedup vs baseline: 1.0769x; 1.0769x over previous
//
#include <hip/hip_runtime.h>
#include <hip/hip_bf16.h>
#include <math.h>

#define HID 2048
#define NH 16
#define NKV 8
#define HD 128
#define SEQ 2048
#define EPS 1e-6f
#define SCALE 0.08838834764831845f  // 128^-0.5

typedef __attribute__((ext_vector_type(8))) short bf8_t;   // 8 bf16 (4 VGPRs)
typedef __attribute__((ext_vector_type(4))) float f4_t;    // 4 fp32

__device__ __forceinline__ short f2bf(float f) {
    union { __hip_bfloat16 h; short s; } u;
    u.h = __float2bfloat16(f);
    return u.s;
}
__device__ __forceinline__ float bf2f(short s) {
    union { short s; __hip_bfloat16 h; } u;
    u.s = s;
    return __bfloat162float(u.h);
}
__device__ __forceinline__ bf8_t pack8(const float4& a, const float4& b) {
    bf8_t r;
    r[0] = f2bf(a.x); r[1] = f2bf(a.y); r[2] = f2bf(a.z); r[3] = f2bf(a.w);
    r[4] = f2bf(b.x); r[5] = f2bf(b.y); r[6] = f2bf(b.z); r[7] = f2bf(b.w);
    return r;
}
// async global->LDS DMA, 16 B per lane; lds dest = wave-uniform base + lane*16
__device__ __forceinline__ void gload16(const short* g, short* l) {
    __builtin_amdgcn_global_load_lds(
        (const __attribute__((address_space(1))) unsigned int*)g,
        (__attribute__((address_space(3))) unsigned int*)l, 16, 0, 0);
}

__device__ __forceinline__ float wave_reduce_sum(float v) {
#pragma unroll
    for (int off = 32; off > 0; off >>= 1) v += __shfl_xor(v, off);
    return v;
}

// ---------------- 1. fused prep: f2bf(w_qkv) | f2bf(w_o) | hidden RMSNorm ------
__global__ __launch_bounds__(256) void prep_kernel(
    const float* __restrict__ w_qkv, short* __restrict__ wqb,
    const float* __restrict__ w_o, short* __restrict__ wob,
    const float* __restrict__ x, const float* __restrict__ w,
    short* __restrict__ out) {
    int bid = blockIdx.x;
    int tid = threadIdx.x;
    if (bid < 4096) {
        int i = bid * 256 + tid;
        float4 a = *(const float4*)(w_qkv + (size_t)i * 8);
        float4 b = *(const float4*)(w_qkv + (size_t)i * 8 + 4);
        *(bf8_t*)(wqb + (size_t)i * 8) = pack8(a, b);
        return;
    }
    if (bid < 6144) {
        int i = (bid - 4096) * 256 + tid;
        float4 a = *(const float4*)(w_o + (size_t)i * 8);
        float4 b = *(const float4*)(w_o + (size_t)i * 8 + 4);
        *(bf8_t*)(wob + (size_t)i * 8) = pack8(a, b);
        return;
    }
    int row = bid - 6144;
    const float* xr = x + (size_t)row * HID;
    float4 a = *(const float4*)(xr + tid * 8);
    float4 b = *(const float4*)(xr + tid * 8 + 4);
    float ss = a.x * a.x + a.y * a.y + a.z * a.z + a.w * a.w +
               b.x * b.x + b.y * b.y + b.z * b.z + b.w * b.w;
    ss = wave_reduce_sum(ss);
    __shared__ float part[4];
    __shared__ float s_scale;
    if ((tid & 63) == 0) part[tid >> 6] = ss;
    __syncthreads();
    if (tid == 0) {
        float t = part[0] + part[1] + part[2] + part[3];
        s_scale = rsqrtf(t / (float)HID + EPS);
    }
    __syncthreads();
    float sc = s_scale;
    float4 wa = *(const float4*)(w + tid * 8);
    float4 wb = *(const float4*)(w + tid * 8 + 4);
    float4 oa = make_float4(a.x * sc * wa.x, a.y * sc * wa.y,
                            a.z * sc * wa.z, a.w * sc * wa.w);
    float4 ob = make_float4(b.x * sc * wb.x, b.y * sc * wb.y,
                            b.z * sc * wb.z, b.w * sc * wb.w);
    *(bf8_t*)(out + (size_t)row * HID + tid * 8) = pack8(oa, ob);
}

// ---------------- 2/5. bf16 MFMA GEMM: C = A @ B^T, BK=64 ----------------
template <int MODE>
__global__ __launch_bounds__(256) void gemm_mfma_kernel(
    const short* __restrict__ A, const short* __restrict__ B,
    float* __restrict__ Cf, short* __restrict__ Q, short* __restrict__ Kp,
    short* __restrict__ Vr, int M, int N, int K) {
    __shared__ short As[128][64];
    __shared__ short Bs[128][64];
    int tid = threadIdx.x;
    int wv = tid >> 6, lane = tid & 63;
    int n16 = lane & 15, qd = lane >> 4;
    int m0 = blockIdx.y * 128, n0 = blockIdx.x * 128;
    int wm = (wv >> 1) * 64, wn = (wv & 1) * 64;
    int sr8 = lane >> 3, slot = lane & 7;

    size_t ainv[4], binv[4];
#pragma unroll
    for (int it = 0; it < 4; ++it) {
        int row = wv * 32 + it * 8 + sr8;
        int chunk = (slot - row) & 7;
        ainv[it] = (size_t)(m0 + row) * K + chunk * 8;
        binv[it] = (size_t)(n0 + row) * K + chunk * 8;
    }

    f4_t acc[4][4];
#pragma unroll
    for (int i = 0; i < 4; ++i)
#pragma unroll
        for (int j = 0; j < 4; ++j) acc[i][j] = (f4_t){0.f, 0.f, 0.f, 0.f};

    for (int k0 = 0; k0 < K; k0 += 64) {
        __syncthreads();
#pragma unroll
        for (int it = 0; it < 4; ++it) {
            gload16(A + ainv[it] + k0, &As[wv * 32 + it * 8][0]);
            gload16(B + binv[it] + k0, &Bs[wv * 32 + it * 8][0]);
        }
        __syncthreads();

        bf8_t af[4][2], bf[4][2];
#pragma unroll
        for (int t = 0; t < 4; ++t)
#pragma unroll
            for (int ks = 0; ks < 2; ++ks) {
                int ar = wm + t * 16 + n16;
                af[t][ks] = *(const bf8_t*)&As[ar][(((ks * 4 + qd) + ar) & 7) * 8];
                int br = wn + t * 16 + n16;
                bf[t][ks] = *(const bf8_t*)&Bs[br][(((ks * 4 + qd) + br) & 7) * 8];
            }
#pragma unroll
        for (int ks = 0; ks < 2; ++ks)
#pragma unroll
            for (int mt = 0; mt < 4; ++mt)
#pragma unroll
                for (int nt = 0; nt < 4; ++nt)
                    acc[mt][nt] = __builtin_amdgcn_mfma_f32_16x16x32_bf16(
                        af[mt][ks], bf[nt][ks], acc[mt][nt], 0, 0, 0);
    }

#pragma unroll
    for (int mt = 0; mt < 4; ++mt)
#pragma unroll
        for (int nt = 0; nt < 4; ++nt)
#pragma unroll
            for (int r = 0; r < 4; ++r) {
                int gm = m0 + wm + mt * 16 + qd * 4 + r;
                int gn = n0 + wn + nt * 16 + n16;
                float v = acc[mt][nt][r];
                if (MODE == 0) {
                    Cf[(size_t)gm * N + gn] = v;
                } else {
                    if (gn < NH * HD)
                        Q[(size_t)gm * (NH * HD) + gn] = f2bf(v);
                    else if (gn < (NH + NKV) * HD)
                        Kp[(size_t)gm * (NKV * HD) + (gn - NH * HD)] = f2bf(v);
                    else
                        Vr[(size_t)gm * (NKV * HD) + (gn - (NH + NKV) * HD)] = f2bf(v);
                }
            }
}

// ---------------- 3. fused mid: V transpose | q/k RMSNorm + RoPE ----------------
__global__ __launch_bounds__(256) void mid_kernel(
    const short* __restrict__ vr, short* __restrict__ vt,
    short* __restrict__ q, short* __restrict__ k,
    const float* __restrict__ qw, const float* __restrict__ kw,
    const int* __restrict__ pos) {
    int bid = blockIdx.x;
    int tid = threadIdx.x;
    if (bid < 512) {  // ---- V transpose, 64x64 tile ----
        __shared__ short t[64][64];
        int s0 = (bid & 31) * 64, d0 = (bid >> 5) * 64;
        int sl = tid >> 3, ch = tid & 7;
#pragma unroll
        for (int it = 0; it < 2; ++it) {
            int s_local = it * 32 + sl;
            bf8_t vv = *(const bf8_t*)(vr + (size_t)(s0 + s_local) * (NKV * HD) + d0 + ch * 8);
            *(bf8_t*)&t[s_local][((ch + s_local) & 7) * 8] = vv;
        }
        __syncthreads();
#pragma unroll
        for (int it = 0; it < 2; ++it) {
            int d_local = it * 32 + sl;
            int sbase = ch * 8;
            bf8_t o;
#pragma unroll
            for (int j = 0; j < 8; ++j) {
                int s = sbase + j;
                o[j] = t[s][(((d_local >> 3) + s) & 7) * 8 + (d_local & 7)];
            }
            *(bf8_t*)(vt + (size_t)(d0 + d_local) * SEQ + s0 + sbase) = o;
        }
        return;
    }
    // ---- q/k RMSNorm + RoPE: two 128-thread units per block ----
    int u = (bid - 512) * 2 + (tid >> 7);
    int ui = tid >> 7, d = tid & 127;
    int s = u / 24, hh = u % 24;
    short* ptr;
    const float* w;
    if (hh < NH) {
        ptr = q + (size_t)s * (NH * HD) + hh * HD;
        w = qw;
    } else {
        ptr = k + (size_t)s * (NKV * HD) + (hh - NH) * HD;
        w = kw;
    }
    float x = bf2f(ptr[d]);
    float ss = wave_reduce_sum(x * x);
    __shared__ float part[2][2];
    if ((d & 63) == 0) part[ui][d >> 6] = ss;
    __syncthreads();
    float tot = part[ui][0] + part[ui][1];
    float xn = x * rsqrtf(tot / (float)HD + EPS) * w[d];
    __shared__ float sh[2][HD];
    sh[ui][d] = xn;
    __syncthreads();
    int j = d & 63;
    float inv = __expf((float)j * -0.14391156831f);  // 10000^(-j/64), fast exp
    float fr = (float)pos[s] * inv;
    float sn, cs;
    __sincosf(fr, &sn, &cs);
    float o;
    if (d < 64)
        o = xn * cs - sh[ui][d + 64] * sn;
    else
        o = xn * cs + sh[ui][d - 64] * sn;
    ptr[d] = f2bf(o);
}

// ---------------- 4. MFMA flash attention v5 (128 q-rows, uniform 2-chunk) ------
// 256 threads = 4 waves; 128 q-rows/block (32/wave as 2 groups sharing K/V frags);
// every q-tile split into 2 equal k-chunks (qt+1 tiles each) -> exactly 512
// blocks = 2/CU, pair (i, i+256) = same head, qt desc/asc -> per-CU sum = 17
// tiles. All blocks write unnormalized partials (to d_out scratch) + (m,l).
__device__ __forceinline__ void attn_stage(
    short (&kb)[64][128], short (&vb)[128][64],
    const short* __restrict__ kg, const short* __restrict__ vg,
    int t0, const int (&kinv)[4], const int (&vinv)[4], int wv) {
#pragma unroll
    for (int it = 0; it < 4; ++it) {
        gload16(kg + (size_t)t0 * (NKV * HD) + kinv[it], &kb[wv * 16 + it * 4][0]);
        gload16(vg + t0 + vinv[it], &vb[wv * 32 + it * 8][0]);
    }
}

__device__ __forceinline__ void attn_tile(
    const short (&kb)[64][128], const short (&vb)[128][64],
    short (&psh)[4][2][16][64],
    const bf8_t (&qf)[2][4], f4_t (&of)[2][8],
    float (&m_i)[2][4], float (&l_p)[2][4],
    int wv, int n, int qd, int koff) {
    f4_t sc[2][4];
#pragma unroll
    for (int g = 0; g < 2; ++g)
#pragma unroll
        for (int kk = 0; kk < 4; ++kk) sc[g][kk] = (f4_t){0.f, 0.f, 0.f, 0.f};
#pragma unroll
    for (int kk = 0; kk < 4; ++kk) {
        int key = kk * 16 + n;
#pragma unroll
        for (int ks = 0; ks < 4; ++ks) {
            bf8_t kf = *(const bf8_t*)&kb[key][(((ks * 4 + qd) + key) & 15) * 8];
            sc[0][kk] = __builtin_amdgcn_mfma_f32_16x16x32_bf16(qf[0][ks], kf, sc[0][kk], 0, 0, 0);
            sc[1][kk] = __builtin_amdgcn_mfma_f32_16x16x32_bf16(qf[1][ks], kf, sc[1][kk], 0, 0, 0);
        }
    }
#pragma unroll
    for (int g = 0; g < 2; ++g) {
        int rows0 = wv * 32 + g * 16;
        bool needm = (koff + 63 > rows0);  // wave-uniform
#pragma unroll
        for (int kk = 0; kk < 4; ++kk)
#pragma unroll
            for (int r = 0; r < 4; ++r) {
                float s = sc[g][kk][r] * SCALE;
                if (needm && (koff + kk * 16 + n > rows0 + qd * 4 + r)) s = -1e30f;
                sc[g][kk][r] = s;
            }
#pragma unroll
        for (int r = 0; r < 4; ++r) {
            float mx = fmaxf(fmaxf(sc[g][0][r], sc[g][1][r]),
                             fmaxf(sc[g][2][r], sc[g][3][r]));
#pragma unroll
            for (int off = 1; off < 16; off <<= 1) mx = fmaxf(mx, __shfl_xor(mx, off));
            float mnew = fmaxf(m_i[g][r], mx);
            float al = __expf(m_i[g][r] - mnew);
            m_i[g][r] = mnew;
            float lsum = 0.f;
            int row = qd * 4 + r;
#pragma unroll
            for (int kk = 0; kk < 4; ++kk) {
                float p = __expf(sc[g][kk][r] - mnew);
                psh[wv][g][row][((kk * 16 + n) + row * 8) & 63] = f2bf(p);
                lsum += p;
            }
            l_p[g][r] = l_p[g][r] * al + lsum;
#pragma unroll
            for (int nb = 0; nb < 8; ++nb) of[g][nb][r] *= al;
        }
    }
    __builtin_amdgcn_wave_barrier();  // psh write->read, same wave (in-order LDS)
#pragma unroll
    for (int ks2 = 0; ks2 < 2; ++ks2) {
        bf8_t pf0 = *(const bf8_t*)&psh[wv][0][n][((ks2 * 32 + qd * 8) + n * 8) & 63];
        bf8_t pf1 = *(const bf8_t*)&psh[wv][1][n][((ks2 * 32 + qd * 8) + n * 8) & 63];
#pragma unroll
        for (int nb = 0; nb < 8; ++nb) {
            int dim = nb * 16 + n;
            bf8_t vf = *(const bf8_t*)&vb[dim][(((ks2 * 4 + qd) + dim) & 7) * 8];
            of[0][nb] = __builtin_amdgcn_mfma_f32_16x16x32_bf16(pf0, vf, of[0][nb], 0, 0, 0);
            of[1][nb] = __builtin_amdgcn_mfma_f32_16x16x32_bf16(pf1, vf, of[1][nb], 0, 0, 0);
        }
    }
}

__global__ __launch_bounds__(256, 2) void attn_chunk_kernel(
    const short* __restrict__ q, const short* __restrict__ k,
    const short* __restrict__ vt, short* __restrict__ opart,
    float* __restrict__ ml) {
    __shared__ short kbufA[64][128], kbufB[64][128];
    __shared__ short vbufA[128][64], vbufB[128][64];
    __shared__ short psh[4][2][16][64];   // total LDS = 80 KB -> 2 blocks/CU

    int tid = threadIdx.x;
    int wv = tid >> 6, lane = tid & 63;
    int n = lane & 15, qd = lane >> 4;

    int i = blockIdx.x;               // 512 blocks
    int hs = i >> 8, p = i & 255;
    int h = p >> 4;
    int qt = hs ? (p & 15) : (15 - (p & 15));
    int c = hs;
    int qbase = qt * 128;
    int tstart = c ? (qt + 1) : 0;
    int tcount = qt + 1;
    int kvh = h >> 1;

    int kinv[4], vinv[4];
#pragma unroll
    for (int it = 0; it < 4; ++it) {
        int key = wv * 16 + it * 4 + (lane >> 4);
        int ck = ((lane & 15) - key) & 15;
        kinv[it] = key * (NKV * HD) + kvh * HD + ck * 8;
        int dim = wv * 32 + it * 8 + (lane >> 3);
        int cv = ((lane & 7) - dim) & 7;
        vinv[it] = (kvh * HD + dim) * SEQ + cv * 8;
    }

    bf8_t qf[2][4];
#pragma unroll
    for (int g = 0; g < 2; ++g) {
        const short* qp =
            q + (size_t)(qbase + wv * 32 + g * 16 + n) * (NH * HD) + h * HD + qd * 8;
#pragma unroll
        for (int ks = 0; ks < 4; ++ks) qf[g][ks] = *(const bf8_t*)(qp + ks * 32);
    }

    f4_t of[2][8];
#pragma unroll
    for (int g = 0; g < 2; ++g)
#pragma unroll
        for (int x = 0; x < 8; ++x) of[g][x] = (f4_t){0.f, 0.f, 0.f, 0.f};
    float m_i[2][4] = {{-1e30f, -1e30f, -1e30f, -1e30f},
                       {-1e30f, -1e30f, -1e30f, -1e30f}};
    float l_p[2][4] = {{0.f, 0.f, 0.f, 0.f}, {0.f, 0.f, 0.f, 0.f}};

    attn_stage(kbufA, vbufA, k, vt, tstart * 64, kinv, vinv, wv);
    for (int tt = 0; tt < tcount; tt += 2) {
        __syncthreads();  // drains DMA for tile tt (issued a full tile ago)
        if (tt + 1 < tcount)
            attn_stage(kbufB, vbufB, k, vt, (tstart + tt + 1) * 64, kinv, vinv, wv);
        attn_tile(kbufA, vbufA, psh, qf, of, m_i, l_p, wv, n, qd,
                  (tstart + tt) * 64 - qbase);
        if (tt + 1 < tcount) {
            __syncthreads();
            if (tt + 2 < tcount)
                attn_stage(kbufA, vbufA, k, vt, (tstart + tt + 2) * 64, kinv, vinv, wv);
            attn_tile(kbufB, vbufB, psh, qf, of, m_i, l_p, wv, n, qd,
                      (tstart + tt + 1) * 64 - qbase);
        }
    }

    float lred[2][4];
#pragma unroll
    for (int g = 0; g < 2; ++g)
#pragma unroll
        for (int r = 0; r < 4; ++r) {
            float l = l_p[g][r];
#pragma unroll
            for (int off = 1; off < 16; off <<= 1) l += __shfl_xor(l, off);
            lred[g][r] = l;
        }

    size_t pb = ((size_t)(h * 16 + qt)) * 2 + c;
    short* op = opart + pb * (128 * 128);
#pragma unroll
    for (int g = 0; g < 2; ++g)
#pragma unroll
        for (int nb = 0; nb < 8; ++nb)
#pragma unroll
            for (int r = 0; r < 4; ++r) {
                int rl = wv * 32 + g * 16 + qd * 4 + r;
                op[rl * 128 + nb * 16 + n] = f2bf(of[g][nb][r]);
            }
    if (n == 0) {
#pragma unroll
        for (int g = 0; g < 2; ++g)
#pragma unroll
            for (int r = 0; r < 4; ++r) {
                int rl = wv * 32 + g * 16 + qd * 4 + r;
                ml[pb * 256 + rl * 2] = m_i[g][r];
                ml[pb * 256 + rl * 2 + 1] = lred[g][r];
            }
    }
}

// ---------------- 4b. merge the two k-chunk partials per q-tile ----------------
__global__ __launch_bounds__(256) void attn_merge_kernel(
    const short* __restrict__ opart, const float* __restrict__ ml,
    short* __restrict__ o) {
    int bid = blockIdx.x;             // 256: h*16 + qt
    int h = bid >> 4, qt = bid & 15;
    int tid = threadIdx.x;
    int r = tid >> 1, hf = tid & 1;   // row 0..127, dim half
    size_t pb0 = ((size_t)(h * 16 + qt)) * 2;
    size_t pb1 = pb0 + 1;
    float m0 = ml[pb0 * 256 + r * 2], l0 = ml[pb0 * 256 + r * 2 + 1];
    float m1 = ml[pb1 * 256 + r * 2], l1 = ml[pb1 * 256 + r * 2 + 1];
    float M = fmaxf(m0, m1);
    float w0 = __expf(m0 - M), w1 = __expf(m1 - M);
    float invL = 1.0f / (w0 * l0 + w1 * l1);
    int row = qt * 128 + r;
#pragma unroll
    for (int j = 0; j < 8; ++j) {
        int d0 = hf * 64 + j * 8;
        bf8_t a = *(const bf8_t*)(opart + pb0 * (128 * 128) + r * 128 + d0);
        bf8_t b = *(const bf8_t*)(opart + pb1 * (128 * 128) + r * 128 + d0);
        bf8_t e;
#pragma unroll
        for (int x = 0; x < 8; ++x)
            e[x] = f2bf((w0 * bf2f(a[x]) + w1 * bf2f(b[x])) * invL);
        *(bf8_t*)(o + (size_t)row * (NH * HD) + h * HD + d0) = e;
    }
}

// ---------------- launch ----------------
extern "C" void kernel_launch(void* const* d_in, const int* in_sizes, int n_in,
                              void* d_out, int out_size, void* d_ws, size_t ws_size,
                              hipStream_t stream) {
    const int* positions   = (const int*)d_in[0];
    const float* hidden    = (const float*)d_in[1];
    const float* ln_w      = (const float*)d_in[2];
    const float* w_qkv     = (const float*)d_in[3];
    const float* w_o       = (const float*)d_in[4];
    const float* q_norm_w  = (const float*)d_in[5];
    const float* k_norm_w  = (const float*)d_in[6];
    float* out = (float*)d_out;

    char* base = (char*)d_ws;
    short* hnb   = (short*)(base);                        // 8 MB: hn bf16 -> attn-out bf16
    short* wqb   = (short*)(base + ((size_t)8 << 20));    // 16 MB: w_qkv bf16 (dead after gemm1)
    short* vtb   = (short*)(base + ((size_t)8 << 20));    // 4 MB: v^T (dead wqb region)
    float* mlbuf = (float*)(base + ((size_t)12 << 20));   // 512 KB: m/l partials (dead wqb)
    short* wob   = (short*)(base + ((size_t)24 << 20));   // 8 MB: w_o bf16
    short* qbf   = (short*)(base + ((size_t)32 << 20));   // 8 MB: q bf16
    short* kbf   = (short*)(base + ((size_t)40 << 20));   // 4 MB: k bf16
    short* vrow  = (short*)(base + ((size_t)44 << 20));   // 4 MB: v bf16 row-major
    short* opart = (short*)d_out;                         // 16 MB scratch until gemm2

    prep_kernel<<<8192, 256, 0, stream>>>(w_qkv, wqb, w_o, wob, hidden, ln_w, hnb);
    gemm_mfma_kernel<1><<<dim3(32, 16), 256, 0, stream>>>(
        hnb, wqb, nullptr, qbf, kbf, vrow, SEQ, (NH + 2 * NKV) * HD, HID);
    mid_kernel<<<512 + 24576, 256, 0, stream>>>(
        vrow, vtb, qbf, kbf, q_norm_w, k_norm_w, positions);
    attn_chunk_kernel<<<512, 256, 0, stream>>>(qbf, kbf, vtb, opart, mlbuf);
    attn_merge_kernel<<<256, 256, 0, stream>>>(opart, mlbuf, hnb);
    gemm_mfma_kernel<0><<<dim3(16, 16), 256, 0, stream>>>(
        hnb, wob, out, nullptr, nullptr, nullptr, SEQ, NH * HD, HID);
}